// Round 1
// baseline (670.939 us; speedup 1.0000x reference)
//
#include <hip/hip_runtime.h>

// Problem constants (from reference)
constexpr int NSAMP  = 2048;
constexpr int NDIM   = 3072;   // H*W*C = 32*32*3
constexpr int NTRANS = 3072;   // NKERNEL*NCOMP = 192*16
constexpr int NBIN   = 200;
constexpr int BLK    = 256;
constexpr int PER_T  = NDIM / BLK;  // 12
constexpr int DIFF_STRIDE = 17;     // pad: bank-conflict-free diff layout

__global__ __launch_bounds__(BLK)
void cpst_fused(const float* __restrict__ data,     // (N, NDIM)
                const int*   __restrict__ label,    // (N,)
                const float* __restrict__ B,        // (192, 16, 16) orthogonal blocks
                const float* __restrict__ kx,       // (10, NTRANS, NBIN)
                const float* __restrict__ ky,
                const float* __restrict__ kd,
                float* __restrict__ out,            // (N, NDIM)
                float* __restrict__ logj)           // (N,)
{
    __shared__ float s_data[NDIM];
    __shared__ float s_diff[192 * DIFF_STRIDE];
    __shared__ float s_part[4];

    const int n   = blockIdx.x;
    const int tid = threadIdx.x;

    // ---- stage 0: load data row into LDS (coalesced) ----
    const float* drow = data + (size_t)n * NDIM;
    #pragma unroll
    for (int j = 0; j < PER_T; ++j)
        s_data[tid + BLK * j] = drow[tid + BLK * j];
    __syncthreads();

    const int cls = label[n];  // block-uniform -> scalar load
    const size_t kbase = (size_t)cls * NTRANS * NBIN;
    const float* kxc = kx + kbase;
    const float* kyc = ky + kbase;
    const float* kdc = kd + kbase;

    float lj_sum = 0.f;

    // ---- stage 1+2: forward block transform + spline, fused per t ----
    #pragma unroll 1
    for (int j = 0; j < PER_T; ++j) {
        const int t = tid + BLK * j;
        const int p = t >> 4;      // patch index 0..191
        const int c = t & 15;      // component 0..15
        // patch -> (nh, nw, ch):  p = (nh*8 + nw)*3 + ch
        const int nh  = p / 24;
        const int rem = p - nh * 24;
        const int nw  = rem / 3;
        const int ch  = rem - nw * 3;
        // flat dim of patch pixel i: ((nh*4 + i/4)*32 + (nw*4 + i%4))*3 + ch
        const int rowbase = nh * 4 * 96 + nw * 4 * 3 + ch;

        const float* Bp = B + p * 256 + c;  // B[p][i][c], stride 16 over i
        float x = 0.f;
        #pragma unroll
        for (int i = 0; i < 16; ++i) {
            const int row = rowbase + (i >> 2) * 96 + (i & 3) * 3;
            x += s_data[row] * Bp[i * 16];
        }

        // ---- rational-quadratic spline with linear extrapolation ----
        const float* xx = kxc + (size_t)t * NBIN;
        const float* yy = kyc + (size_t)t * NBIN;
        const float* dd = kdc + (size_t)t * NBIN;
        const float lo = xx[0];
        const float hi = xx[NBIN - 1];

        float y, lj;
        if (x < lo) {
            const float d0 = dd[0];
            y  = yy[0] + (x - lo) * d0;
            lj = __logf(d0);
        } else if (x > hi) {
            const float dK = dd[NBIN - 1];
            y  = yy[NBIN - 1] + (x - hi) * dK;
            lj = __logf(dK);
        } else {
            // binary search: k = max index with xx[k] <= x  (x in [lo,hi])
            int klo = 0, khi = NBIN;
            while (khi - klo > 1) {
                const int mid = (klo + khi) >> 1;
                const bool le = (xx[mid] <= x);
                klo = le ? mid : klo;
                khi = le ? khi : mid;
            }
            int k = klo;
            if (k > NBIN - 2) k = NBIN - 2;

            const float xk  = xx[k],     xk1 = xx[k + 1];
            const float yk  = yy[k],     yk1 = yy[k + 1];
            const float dk  = dd[k],     dk1 = dd[k + 1];

            const float wdt     = xk1 - xk;
            const float inv_wdt = __fdividef(1.f, wdt);
            const float dy      = yk1 - yk;
            const float s       = dy * inv_wdt;
            const float xi      = (x - xk) * inv_wdt;
            const float om      = 1.f - xi;
            const float denom   = s + (dk1 + dk - 2.f * s) * xi * om;
            const float num     = dy * (s * xi * xi + dk * xi * om);
            y  = yk + __fdividef(num, denom);
            lj = 2.f * __logf(s)
               + __logf(dk1 * xi * xi + 2.f * s * xi * om + dk * om * om)
               - 2.f * __logf(denom);
        }

        s_diff[p * DIFF_STRIDE + c] = y - x;   // (data1 - data0)[t]
        lj_sum += lj;
    }

    // ---- logj reduction: wave shuffle + 4 partials ----
    #pragma unroll
    for (int off = 32; off > 0; off >>= 1)
        lj_sum += __shfl_down(lj_sum, off);
    if ((tid & 63) == 0) s_part[tid >> 6] = lj_sum;
    __syncthreads();   // also covers s_diff for stage 3
    if (tid == 0)
        logj[n] = s_part[0] + s_part[1] + s_part[2] + s_part[3];

    // ---- stage 3: out = data + diff @ wT^T  (per-patch 16-MAC) ----
    float* orow = out + (size_t)n * NDIM;
    #pragma unroll 1
    for (int j = 0; j < PER_T; ++j) {
        const int d  = tid + BLK * j;
        const int ch = d % 3;
        const int hw = d / 3;
        const int w  = hw & 31;
        const int h  = hw >> 5;
        const int p  = ((h >> 2) * 8 + (w >> 2)) * 3 + ch;
        const int i  = (h & 3) * 4 + (w & 3);

        const float* Bp = B + p * 256 + i * 16;       // contiguous 16 floats
        const float* dp = s_diff + p * DIFF_STRIDE;   // conflict-free banks
        float acc = s_data[d];
        #pragma unroll
        for (int cc = 0; cc < 16; ++cc)
            acc += dp[cc] * Bp[cc];
        orow[d] = acc;
    }
}

extern "C" void kernel_launch(void* const* d_in, const int* in_sizes, int n_in,
                              void* d_out, int out_size, void* d_ws, size_t ws_size,
                              hipStream_t stream) {
    const float* data  = (const float*)d_in[0];
    const int*   label = (const int*)  d_in[1];
    const float* B     = (const float*)d_in[2];
    const float* kx    = (const float*)d_in[3];
    const float* ky    = (const float*)d_in[4];
    const float* kd    = (const float*)d_in[5];

    float* out  = (float*)d_out;                       // (N, NDIM) first
    float* logj = (float*)d_out + (size_t)NSAMP * NDIM; // then (N,)

    cpst_fused<<<NSAMP, BLK, 0, stream>>>(data, label, B, kx, ky, kd, out, logj);
}

// Round 2
// 292.673 us; speedup vs baseline: 2.2925x; 2.2925x over previous
//
#include <hip/hip_runtime.h>

// Problem constants (from reference)
constexpr int NSAMP  = 2048;
constexpr int NDIM   = 3072;   // H*W*C = 32*32*3
constexpr int NTRANS = 3072;   // NKERNEL*NCOMP = 192*16
constexpr int NBIN   = 200;
constexpr int NCLASS = 10;
constexpr int NPATCH = 192;
constexpr int BLK    = 256;
constexpr int PER_T  = NDIM / BLK;  // 12
constexpr int DIFF_STRIDE = 17;     // bank-conflict-free reconstruction reads

// ---------------- P0: deterministic class bucketing ----------------
// slot[n] = cls_off[label[n]] + rank of n among earlier same-class samples.
__global__ __launch_bounds__(1024)
void p0_bucket(const int* __restrict__ label,
               int* __restrict__ slot,        // (NSAMP)
               int* __restrict__ cls_off,     // (NCLASS+1)
               float* __restrict__ logj_slot) // (NSAMP), zeroed here
{
    __shared__ int s_lab[NSAMP];
    __shared__ int s_cnt[NCLASS];
    __shared__ int s_off[NCLASS + 1];
    const int tid = threadIdx.x;

    for (int i = tid; i < NSAMP; i += 1024) {
        s_lab[i] = label[i];
        logj_slot[i] = 0.f;
    }
    __syncthreads();

    const int n0 = tid * 2, n1 = n0 + 1;
    const int c0 = s_lab[n0], c1 = s_lab[n1];
    int rank0 = 0, rank1 = 0;
    for (int m = 0; m < n0; ++m) {       // broadcast LDS reads (uniform m)
        const int l = s_lab[m];
        rank0 += (l == c0);
        rank1 += (l == c1);
    }
    rank1 += (c0 == c1);

    if (tid < NCLASS) {
        int cnt = 0;
        for (int m = 0; m < NSAMP; ++m) cnt += (s_lab[m] == tid);
        s_cnt[tid] = cnt;
    }
    __syncthreads();
    if (tid == 0) {
        int acc = 0;
        for (int c = 0; c < NCLASS; ++c) { s_off[c] = acc; acc += s_cnt[c]; }
        s_off[NCLASS] = acc;
    }
    __syncthreads();

    slot[n0] = s_off[c0] + rank0;
    slot[n1] = s_off[c1] + rank1;
    if (tid <= NCLASS) cls_off[tid] = s_off[tid];
}

// ---------------- A: per-patch projection x = data @ wT ----------------
__global__ __launch_bounds__(BLK)
void pA_project(const float* __restrict__ data,  // (N, NDIM)
                const float* __restrict__ B,     // (192,16,16)
                const int*   __restrict__ slot,
                float* __restrict__ xbuf)        // (N, NTRANS) in slot order
{
    __shared__ float s_data[NDIM];
    const int n = blockIdx.x;
    const int tid = threadIdx.x;

    const float* drow = data + (size_t)n * NDIM;
    #pragma unroll
    for (int j = 0; j < PER_T; ++j)
        s_data[tid + BLK * j] = drow[tid + BLK * j];
    __syncthreads();

    float* xrow = xbuf + (size_t)slot[n] * NTRANS;

    #pragma unroll 1
    for (int j = 0; j < PER_T; ++j) {
        const int t = tid + BLK * j;
        const int p = t >> 4;
        const int c = t & 15;
        const int nh  = p / 24;
        const int rem = p - nh * 24;
        const int nw  = rem / 3;
        const int ch  = rem - nw * 3;
        const int rowbase = nh * 4 * 96 + nw * 4 * 3 + ch;

        const float* Bp = B + p * 256 + c;
        float x = 0.f;
        #pragma unroll
        for (int i = 0; i < 16; ++i) {
            const int row = rowbase + (i >> 2) * 96 + (i & 3) * 3;
            x += s_data[row] * Bp[i * 16];
        }
        xrow[t] = x;
    }
}

// ---------------- B: spline with LDS-staged knots ----------------
// One block per (patch, class). Knots for the 16 coords of this patch are
// loaded once into LDS; samples of the class are contiguous slots.
__global__ __launch_bounds__(BLK)
void pB_spline(const float* __restrict__ kx,   // (10, NTRANS, NBIN)
               const float* __restrict__ ky,
               const float* __restrict__ kd,
               const int*   __restrict__ cls_off,
               float* __restrict__ xbuf,        // in: x, out: diff (in place)
               float* __restrict__ logj_slot)
{
    __shared__ float s_kx[16 * NBIN];
    __shared__ float s_ky[16 * NBIN];
    __shared__ float s_kd[16 * NBIN];

    const int p   = blockIdx.x;   // 0..191
    const int c   = blockIdx.y;   // 0..9
    const int tid = threadIdx.x;
    const int t0  = p * 16;

    // Stage 16 contiguous knot rows per array: 3200 floats = 800 float4 each.
    const size_t kofs = ((size_t)c * NTRANS + t0) * NBIN;
    const float4* gx = (const float4*)(kx + kofs);
    const float4* gy = (const float4*)(ky + kofs);
    const float4* gd = (const float4*)(kd + kofs);
    float4* lx = (float4*)s_kx;
    float4* ly = (float4*)s_ky;
    float4* ld = (float4*)s_kd;
    for (int i = tid; i < 16 * NBIN / 4; i += BLK) {
        lx[i] = gx[i];
        ly[i] = gy[i];
        ld[i] = gd[i];
    }
    __syncthreads();

    const int beg = cls_off[c];
    const int end = cls_off[c + 1];

    for (int sbase = beg; sbase < end; sbase += BLK) {
        const int sl = sbase + tid;
        if (sl >= end) break;

        float* xrow = xbuf + (size_t)sl * NTRANS + t0;  // 64B-aligned line
        float4 v0 = ((const float4*)xrow)[0];
        float4 v1 = ((const float4*)xrow)[1];
        float4 v2 = ((const float4*)xrow)[2];
        float4 v3 = ((const float4*)xrow)[3];
        float xs[16] = {v0.x, v0.y, v0.z, v0.w, v1.x, v1.y, v1.z, v1.w,
                        v2.x, v2.y, v2.z, v2.w, v3.x, v3.y, v3.z, v3.w};

        float lj_sum = 0.f;
        #pragma unroll
        for (int j = 0; j < 16; ++j) {
            const float* xx = &s_kx[j * NBIN];
            const float* yy = &s_ky[j * NBIN];
            const float* dd = &s_kd[j * NBIN];
            const float x  = xs[j];
            const float lo = xx[0];
            const float hi = xx[NBIN - 1];

            float y, lj;
            if (x < lo) {
                const float d0 = dd[0];
                y  = yy[0] + (x - lo) * d0;
                lj = __logf(d0);
            } else if (x > hi) {
                const float dK = dd[NBIN - 1];
                y  = yy[NBIN - 1] + (x - hi) * dK;
                lj = __logf(dK);
            } else {
                // fixed 8-step binary search: max k with xx[k] <= x
                int klo = 0, khi = NBIN;
                #pragma unroll
                for (int it = 0; it < 8; ++it) {
                    const int mid = (klo + khi) >> 1;
                    const bool le = (xx[mid] <= x);
                    klo = le ? mid : klo;
                    khi = le ? khi : mid;
                }
                int k = klo;
                if (k > NBIN - 2) k = NBIN - 2;

                const float xk = xx[k], xk1 = xx[k + 1];
                const float yk = yy[k], yk1 = yy[k + 1];
                const float dk = dd[k], dk1 = dd[k + 1];

                const float wdt     = xk1 - xk;
                const float inv_wdt = __fdividef(1.f, wdt);
                const float dy      = yk1 - yk;
                const float s       = dy * inv_wdt;
                const float xi      = (x - xk) * inv_wdt;
                const float om      = 1.f - xi;
                const float denom   = s + (dk1 + dk - 2.f * s) * xi * om;
                const float num     = dy * (s * xi * xi + dk * xi * om);
                y  = yk + __fdividef(num, denom);
                lj = 2.f * __logf(s)
                   + __logf(dk1 * xi * xi + 2.f * s * xi * om + dk * om * om)
                   - 2.f * __logf(denom);
            }
            xs[j] = y - x;
            lj_sum += lj;
        }

        ((float4*)xrow)[0] = make_float4(xs[0],  xs[1],  xs[2],  xs[3]);
        ((float4*)xrow)[1] = make_float4(xs[4],  xs[5],  xs[6],  xs[7]);
        ((float4*)xrow)[2] = make_float4(xs[8],  xs[9],  xs[10], xs[11]);
        ((float4*)xrow)[3] = make_float4(xs[12], xs[13], xs[14], xs[15]);
        atomicAdd(logj_slot + sl, lj_sum);
    }
}

// ---------------- C: out = data + diff @ wT^T ----------------
__global__ __launch_bounds__(BLK)
void pC_recon(const float* __restrict__ data,
              const float* __restrict__ B,
              const int*   __restrict__ slot,
              const float* __restrict__ xbuf,      // diff, slot order
              const float* __restrict__ logj_slot,
              float* __restrict__ out,
              float* __restrict__ logj)
{
    __shared__ float s_diff[NPATCH * DIFF_STRIDE];
    const int n   = blockIdx.x;
    const int tid = threadIdx.x;
    const int sl  = slot[n];

    const float4* drow_diff = (const float4*)(xbuf + (size_t)sl * NTRANS);
    for (int i = tid; i < NTRANS / 4; i += BLK) {
        const float4 v = drow_diff[i];
        const int t = i * 4;                       // t%16 in {0,4,8,12}: same patch
        float* dst = &s_diff[(t >> 4) * DIFF_STRIDE + (t & 15)];
        dst[0] = v.x; dst[1] = v.y; dst[2] = v.z; dst[3] = v.w;
    }
    if (tid == 0) logj[n] = logj_slot[sl];
    __syncthreads();

    const float* drow = data + (size_t)n * NDIM;
    float* orow = out + (size_t)n * NDIM;
    #pragma unroll 1
    for (int j = 0; j < PER_T; ++j) {
        const int d  = tid + BLK * j;
        const int ch = d % 3;
        const int hw = d / 3;
        const int w  = hw & 31;
        const int h  = hw >> 5;
        const int p  = ((h >> 2) * 8 + (w >> 2)) * 3 + ch;
        const int i  = (h & 3) * 4 + (w & 3);

        const float* Bp = B + p * 256 + i * 16;
        const float* dp = s_diff + p * DIFF_STRIDE;
        float acc = drow[d];
        #pragma unroll
        for (int cc = 0; cc < 16; ++cc)
            acc += dp[cc] * Bp[cc];
        orow[d] = acc;
    }
}

extern "C" void kernel_launch(void* const* d_in, const int* in_sizes, int n_in,
                              void* d_out, int out_size, void* d_ws, size_t ws_size,
                              hipStream_t stream) {
    const float* data  = (const float*)d_in[0];
    const int*   label = (const int*)  d_in[1];
    const float* B     = (const float*)d_in[2];
    const float* kx    = (const float*)d_in[3];
    const float* ky    = (const float*)d_in[4];
    const float* kd    = (const float*)d_in[5];

    float* out  = (float*)d_out;
    float* logj = (float*)d_out + (size_t)NSAMP * NDIM;

    // ws layout
    char* ws = (char*)d_ws;
    float* xbuf      = (float*)ws;                                    // 25.17 MB
    int*   slot      = (int*)(ws + (size_t)NSAMP * NTRANS * 4);       // 8 KB
    int*   cls_off   = (int*)(ws + (size_t)NSAMP * NTRANS * 4 + NSAMP * 4);
    float* logj_slot = (float*)(ws + (size_t)NSAMP * NTRANS * 4 + NSAMP * 4 + 64);

    p0_bucket <<<1, 1024, 0, stream>>>(label, slot, cls_off, logj_slot);
    pA_project<<<NSAMP, BLK, 0, stream>>>(data, B, slot, xbuf);
    dim3 gridB(NPATCH, NCLASS);
    pB_spline <<<gridB, BLK, 0, stream>>>(kx, ky, kd, cls_off, xbuf, logj_slot);
    pC_recon  <<<NSAMP, BLK, 0, stream>>>(data, B, slot, xbuf, logj_slot, out, logj);
}